// Round 6
// baseline (265.029 us; speedup 1.0000x reference)
//
#include <hip/hip_runtime.h>

#define FN   128    // nodes per graph
#define HDIM 128    // hidden dim
#define NH   4      // heads, layer 0
#define HSZ  32     // head dim, layer 0
#define EB   1024   // base edges per graph
#define ET   1152   // edges incl. self loops
#define RSW  132    // padded LDS row stride (words)
#define CS   33     // chunk stride for feat1 (layer-0 agg output)
#define CHK  4224   // 32*132 = one sgT slice / chunk region

typedef __attribute__((ext_vector_type(8))) short bf16x8;
typedef __attribute__((ext_vector_type(4))) float f32x4;
typedef unsigned int u32;

union U8 { bf16x8 v; u32 u[4]; };

__device__ __forceinline__ u32 pack_hl(float v) {
  const u32 u = __float_as_uint(v);
  const u32 hib = u & 0xFFFF0000u;
  const float lo = v - __uint_as_float(hib);
  return hib | (__float_as_uint(lo) >> 16);
}
__device__ __forceinline__ float unpack_val(u32 p) {
  return __uint_as_float(p & 0xFFFF0000u) + __uint_as_float(p << 16);
}

// 8 packed hi|lo u32 -> hi,lo bf16x8
__device__ __forceinline__ void unpack_frag2(uint4 p0, uint4 p1, bf16x8& hi, bf16x8& lo)
{
  U8 H, L;
  H.u[0] = (p0.x >> 16) | (p0.y & 0xFFFF0000u);
  L.u[0] = (p0.x & 0xFFFFu) | (p0.y << 16);
  H.u[1] = (p0.z >> 16) | (p0.w & 0xFFFF0000u);
  L.u[1] = (p0.z & 0xFFFFu) | (p0.w << 16);
  H.u[2] = (p1.x >> 16) | (p1.y & 0xFFFF0000u);
  L.u[2] = (p1.x & 0xFFFFu) | (p1.y << 16);
  H.u[3] = (p1.z >> 16) | (p1.w & 0xFFFF0000u);
  L.u[3] = (p1.z & 0xFFFFu) | (p1.w << 16);
  hi = H.v; lo = L.v;
}

// 8 f32 -> hi,lo bf16x8 (split-float)
__device__ __forceinline__ void split8(const float* w, bf16x8& hi, bf16x8& lo)
{
  U8 H, L;
  #pragma unroll
  for (int p = 0; p < 4; ++p) {
    const u32 u0 = __float_as_uint(w[2 * p]);
    const u32 u1 = __float_as_uint(w[2 * p + 1]);
    const u32 h0 = u0 & 0xFFFF0000u, h1 = u1 & 0xFFFF0000u;
    const float l0 = w[2 * p]     - __uint_as_float(h0);
    const float l1 = w[2 * p + 1] - __uint_as_float(h1);
    H.u[p] = (u0 >> 16) | h1;
    L.u[p] = (__float_as_uint(l0) >> 16) | (__float_as_uint(l1) & 0xFFFF0000u);
  }
  hi = H.v; lo = L.v;
}

#define MFMA3(ACC, AH, AL, BH, BL)                                          \
  ACC = __builtin_amdgcn_mfma_f32_16x16x32_bf16(AH, BH, ACC, 0, 0, 0);      \
  ACC = __builtin_amdgcn_mfma_f32_16x16x32_bf16(AL, BH, ACC, 0, 0, 0);      \
  ACC = __builtin_amdgcn_mfma_f32_16x16x32_bf16(AH, BL, ACC, 0, 0, 0);

// GEMM (transposed out): dst[ch][node] (packed) = (feat @ W)^T
// A = W^T (global strided dwords), B = feat (LDS). CHUNKED: feat stored as
// 4 head-chunks at stride CS (b32 reads); else [node][RSW] packed (b128).
template<bool CHUNKED>
__device__ __forceinline__ void gemm_T(const u32* src, u32* dst,
                                       const float* __restrict__ W, int t)
{
  const int w = t >> 6, lane = t & 63;
  const int li = lane & 15, quad = lane >> 4;
  const int m0 = (w & 3) * 32;      // ch tile pair
  const int n0 = (w >> 2) * 32;     // node tile pair

  f32x4 acc[2][2];
  #pragma unroll
  for (int i = 0; i < 2; ++i)
    #pragma unroll
    for (int j = 0; j < 2; ++j) acc[i][j] = (f32x4){0.f, 0.f, 0.f, 0.f};

  #pragma unroll
  for (int kc = 0; kc < 4; ++kc) {
    bf16x8 ahi[2], alo[2], bhi[2], blo[2];
    #pragma unroll
    for (int mt = 0; mt < 2; ++mt) {
      const int ch = m0 + mt * 16 + li;
      float wv[8];
      #pragma unroll
      for (int j = 0; j < 8; ++j) wv[j] = W[(kc * 32 + quad * 8 + j) * HDIM + ch];
      split8(wv, ahi[mt], alo[mt]);
    }
    #pragma unroll
    for (int nt = 0; nt < 2; ++nt) {
      const int n = n0 + nt * 16 + li;
      if (CHUNKED) {
        const u32* p = src + kc * CHK + n * CS + quad * 8;
        const uint4 q0 = make_uint4(p[0], p[1], p[2], p[3]);
        const uint4 q1 = make_uint4(p[4], p[5], p[6], p[7]);
        unpack_frag2(q0, q1, bhi[nt], blo[nt]);
      } else {
        const u32* p = src + n * RSW + kc * 32 + quad * 8;
        unpack_frag2(*(const uint4*)p, *(const uint4*)(p + 4), bhi[nt], blo[nt]);
      }
    }
    #pragma unroll
    for (int mt = 0; mt < 2; ++mt)
      #pragma unroll
      for (int nt = 0; nt < 2; ++nt) {
        MFMA3(acc[mt][nt], ahi[mt], alo[mt], bhi[nt], blo[nt]);
      }
  }
  // C/D: col = lane&15 = node, row = quad*4+r = ch  -> store sgT packed
  #pragma unroll
  for (int mt = 0; mt < 2; ++mt)
    #pragma unroll
    for (int nt = 0; nt < 2; ++nt)
      #pragma unroll
      for (int r = 0; r < 4; ++r)
        dst[(m0 + mt * 16 + quad * 4 + r) * RSW + n0 + nt * 16 + li] =
            pack_hl(acc[mt][nt][r]);
}

// ---------------- fully fused per-graph GNN (1024 threads, 16 waves) ----------------
__global__ __launch_bounds__(1024) void gnn_fused_kernel(
    const float* __restrict__ x, const int* __restrict__ ei,
    const float* __restrict__ w_in, const float* __restrict__ b_in,
    const float* __restrict__ g0w, const float* __restrict__ g0as,
    const float* __restrict__ g0ad, const float* __restrict__ g0b,
    const float* __restrict__ bn0g, const float* __restrict__ bn0b,
    const float* __restrict__ bn0m, const float* __restrict__ bn0v,
    const float* __restrict__ g1w, const float* __restrict__ g1as,
    const float* __restrict__ g1ad, const float* __restrict__ g1b,
    const float* __restrict__ bn1g, const float* __restrict__ bn1b,
    const float* __restrict__ bn1m, const float* __restrict__ bn1v,
    const float* __restrict__ w1, const float* __restrict__ b1,
    const float* __restrict__ w2, const float* __restrict__ b2,
    float* __restrict__ out)
{
  __shared__ u32   F[FN * RSW];        // feat0 packed / P0 (f32) / sgT1 packed / feat_final f32
  __shared__ u32   G[FN * RSW];        // sgT0 packed / feat1 chunks / P1 (f32)
  __shared__ float s_alpha[NH * ET];   // exp values (CSR scratch, pool scratch)
  __shared__ int   s_src[ET];          // src | dst<<8
  __shared__ int   s_rp[FN + 1];
  __shared__ float s_es[512];
  __shared__ float s_ed[512];          // logits -> 1/sum

  const int t = threadIdx.x;
  const int b = blockIdx.x;
  const int lane = t & 63;
  const int li = lane & 15, quad = lane >> 4;
  const int aw = t >> 6;
  const int row = t >> 3, sub = t & 7;   // P zero mapping

  // ================= per-block CSR build =================
  int* s_deg  = (int*)s_alpha;
  int* s_fill = s_deg + 128;
  const int e_dst = ei[EB + t];
  const int e_src = ei[t];
  if (t < 2 * FN) s_deg[t] = 0;
  __syncthreads();
  atomicAdd(&s_deg[e_dst], 1);

  // ---- input projection + ReLU -> F (packed feat0 [node][ch])
  {
    const int j = t & 127, q = t >> 7;
    const float wv = w_in[j], bv = b_in[j];
    for (int n = q * 16; n < q * 16 + 16; ++n) {
      const float v = fmaxf(fmaf(x[(size_t)b * FN + n], wv, bv), 0.f);
      F[n * RSW + j] = pack_hl(v);
    }
  }
  __syncthreads();
  if (t < 64) {                          // wave-0 exclusive scan of (deg+1)
    const int v0 = s_deg[2 * t] + 1, v1 = s_deg[2 * t + 1] + 1;
    const int p = v0 + v1;
    int sc = p;
    #pragma unroll
    for (int off = 1; off < 64; off <<= 1) {
      const int o = __shfl_up(sc, off, 64);
      if (t >= off) sc += o;
    }
    s_rp[2 * t] = sc - p;
    s_rp[2 * t + 1] = sc - v1;
    if (t == 63) s_rp[128] = sc;
  }
  __syncthreads();
  {
    const int p = s_rp[e_dst] + atomicAdd(&s_fill[e_dst], 1);
    s_src[p] = e_src | (e_dst << 8);
  }
  if (t < FN) s_src[s_rp[t + 1] - 1] = t | (t << 8);
  __syncthreads();

  // ======================= GAT layer 0: GEMM -> sgT0 (G) =======================
  gemm_T<false>(F, G, g0w, t);
  __syncthreads();

  // logits per (head, node) from sgT0 columns
  if (t < 512) {
    const int hh = t >> 7, n = t & 127;
    float accs = 0.f, accd = 0.f;
    #pragma unroll 4
    for (int d = 0; d < HSZ; ++d) {
      const float v = unpack_val(G[(hh * HSZ + d) * RSW + n]);
      accs = fmaf(v, g0as[hh * HSZ + d], accs);
      accd = fmaf(v, g0ad[hh * HSZ + d], accd);
    }
    s_es[hh * 128 + n] = accs;
    s_ed[hh * 128 + n] = accd;
  }
  __syncthreads();

  // softmax: unnormalized exp -> s_alpha, 1/sum -> s_ed
  if (t < 512) {
    const int hh = t >> 7, n = t & 127;
    const float edv = s_ed[hh * 128 + n];
    const int e0 = s_rp[n], e1 = s_rp[n + 1];
    float mv = -1e30f;
    for (int e = e0; e < e1; ++e) {
      float v = s_es[hh * 128 + (s_src[e] & 127)] + edv;
      v = (v > 0.f) ? v : 0.2f * v;
      s_alpha[hh * ET + e] = v;
      mv = fmaxf(mv, v);
    }
    float sum = 0.f;
    for (int e = e0; e < e1; ++e) {
      const float ex = __expf(s_alpha[hh * ET + e] - mv);
      s_alpha[hh * ET + e] = ex;
      sum += ex;
    }
    s_ed[hh * 128 + n] = 1.f / sum;
  }
  __syncthreads();

  // ======================= layer-0 aggregation as MFMA =======================
  float* Pf = (float*)F;
  // zero P once (cols 0..127)
  {
    const uint4 z = make_uint4(0u, 0u, 0u, 0u);
    *(uint4*)(Pf + row * RSW + sub * 16)      = *(const uint4*)&z;
    *(uint4*)(Pf + row * RSW + sub * 16 + 4)  = *(const uint4*)&z;
    *(uint4*)(Pf + row * RSW + sub * 16 + 8)  = *(const uint4*)&z;
    *(uint4*)(Pf + row * RSW + sub * 16 + 12) = *(const uint4*)&z;
  }
  __syncthreads();

  const int mt_a = aw >> 1, nt_a = aw & 1;   // dst tile (0..7), ch tile (0..1)
  #pragma unroll 1
  for (int hh = 0; hh < NH; ++hh) {
    // scatter alpha (head 0) or delta (heads 1..3) into P  [dst][src] +=
    {
      const int sd = s_src[t];
      float v = s_alpha[hh * ET + t];
      if (hh) v -= s_alpha[(hh - 1) * ET + t];
      atomicAdd(&Pf[(sd >> 8) * RSW + (sd & 127)], v);
      if (t < ET - EB) {
        const int sd2 = s_src[EB + t];
        float v2 = s_alpha[hh * ET + EB + t];
        if (hh) v2 -= s_alpha[(hh - 1) * ET + EB + t];
        atomicAdd(&Pf[(sd2 >> 8) * RSW + (sd2 & 127)], v2);
      }
    }
    __syncthreads();
    // MFMA: out[dst][ch] = P @ sgT-slice(hh); wave owns one 16x16 tile
    f32x4 acc = (f32x4){0.f, 0.f, 0.f, 0.f};
    #pragma unroll
    for (int kc = 0; kc < 4; ++kc) {
      float arr[8];
      const float4 u0 = *(const float4*)(Pf + (mt_a * 16 + li) * RSW + kc * 32 + quad * 8);
      const float4 u1 = *(const float4*)(Pf + (mt_a * 16 + li) * RSW + kc * 32 + quad * 8 + 4);
      arr[0] = u0.x; arr[1] = u0.y; arr[2] = u0.z; arr[3] = u0.w;
      arr[4] = u1.x; arr[5] = u1.y; arr[6] = u1.z; arr[7] = u1.w;
      bf16x8 phi, plo;
      split8(arr, phi, plo);
      const u32* gp = G + (hh * HSZ + nt_a * 16 + li) * RSW + kc * 32 + quad * 8;
      bf16x8 shi, slo;
      unpack_frag2(*(const uint4*)gp, *(const uint4*)(gp + 4), shi, slo);
      MFMA3(acc, phi, plo, shi, slo);
    }
    __syncthreads();   // all reads of G-slice & P done before overwrite
    // epilogue: *1/sum, +bias, BN, relu -> pack -> feat1 chunk (G slice hh)
    {
      const int ch = hh * HSZ + nt_a * 16 + li;
      const float bb = g0b[ch], bm = bn0m[ch];
      const float gs = bn0g[ch] * rsqrtf(bn0v[ch] + 1e-5f), gb = bn0b[ch];
      #pragma unroll
      for (int r = 0; r < 4; ++r) {
        const int dn = mt_a * 16 + quad * 4 + r;
        const float rsv = s_ed[hh * 128 + dn];
        G[hh * CHK + dn * CS + nt_a * 16 + li] =
            pack_hl(fmaxf((acc[r] * rsv + bb - bm) * gs + gb, 0.f));
      }
    }
  }
  __syncthreads();

  // ======================= GAT layer 1: GEMM -> sgT1 (F) =======================
  gemm_T<true>(G, F, g1w, t);
  __syncthreads();

  // logits (1 head) + zero P1 (G) concurrently
  float* Pg = (float*)G;
  {
    const uint4 z = make_uint4(0u, 0u, 0u, 0u);
    *(uint4*)(Pg + row * RSW + sub * 16)      = *(const uint4*)&z;
    *(uint4*)(Pg + row * RSW + sub * 16 + 4)  = *(const uint4*)&z;
    *(uint4*)(Pg + row * RSW + sub * 16 + 8)  = *(const uint4*)&z;
    *(uint4*)(Pg + row * RSW + sub * 16 + 12) = *(const uint4*)&z;
  }
  if (t < FN) {
    const int n = t;
    float a0 = 0.f, a1 = 0.f, d0 = 0.f, d1 = 0.f;
    #pragma unroll 4
    for (int d = 0; d < HDIM; d += 2) {
      const float v0 = unpack_val(F[d * RSW + n]);
      const float v1 = unpack_val(F[(d + 1) * RSW + n]);
      a0 = fmaf(v0, g1as[d], a0); a1 = fmaf(v1, g1as[d + 1], a1);
      d0 = fmaf(v0, g1ad[d], d0); d1 = fmaf(v1, g1ad[d + 1], d1);
    }
    s_es[n] = a0 + a1;
    s_ed[n] = d0 + d1;
  }
  __syncthreads();

  if (t < FN) {
    const int n = t;
    const float edv = s_ed[n];
    const int e0 = s_rp[n], e1 = s_rp[n + 1];
    float mv = -1e30f;
    for (int e = e0; e < e1; ++e) {
      float v = s_es[s_src[e] & 127] + edv;
      v = (v > 0.f) ? v : 0.2f * v;
      s_alpha[e] = v;
      mv = fmaxf(mv, v);
    }
    float sum = 0.f;
    for (int e = e0; e < e1; ++e) {
      const float ex = __expf(s_alpha[e] - mv);
      s_alpha[e] = ex;
      sum += ex;
    }
    s_ed[n] = 1.f / sum;
  }
  __syncthreads();

  // scatter P1
  {
    const int sd = s_src[t];
    atomicAdd(&Pg[(sd >> 8) * RSW + (sd & 127)], s_alpha[t]);
    if (t < ET - EB) {
      const int sd2 = s_src[EB + t];
      atomicAdd(&Pg[(sd2 >> 8) * RSW + (sd2 & 127)], s_alpha[EB + t]);
    }
  }
  __syncthreads();

  // layer-1 aggregation MFMA: wave owns 2x2 tiles
  {
    const int m0 = (aw >> 2) * 32;   // dst tiles
    const int n0 = (aw & 3) * 32;    // ch tiles
    f32x4 acc[2][2];
    #pragma unroll
    for (int i = 0; i < 2; ++i)
      #pragma unroll
      for (int j = 0; j < 2; ++j) acc[i][j] = (f32x4){0.f, 0.f, 0.f, 0.f};
    #pragma unroll
    for (int kc = 0; kc < 4; ++kc) {
      bf16x8 phi[2], plo[2], shi[2], slo[2];
      #pragma unroll
      for (int mt = 0; mt < 2; ++mt) {
        float arr[8];
        const float4 u0 = *(const float4*)(Pg + (m0 + mt * 16 + li) * RSW + kc * 32 + quad * 8);
        const float4 u1 = *(const float4*)(Pg + (m0 + mt * 16 + li) * RSW + kc * 32 + quad * 8 + 4);
        arr[0] = u0.x; arr[1] = u0.y; arr[2] = u0.z; arr[3] = u0.w;
        arr[4] = u1.x; arr[5] = u1.y; arr[6] = u1.z; arr[7] = u1.w;
        split8(arr, phi[mt], plo[mt]);
      }
      #pragma unroll
      for (int nt = 0; nt < 2; ++nt) {
        const u32* p = F + (n0 + nt * 16 + li) * RSW + kc * 32 + quad * 8;
        unpack_frag2(*(const uint4*)p, *(const uint4*)(p + 4), shi[nt], slo[nt]);
      }
      #pragma unroll
      for (int mt = 0; mt < 2; ++mt)
        #pragma unroll
        for (int nt = 0; nt < 2; ++nt) {
          MFMA3(acc[mt][nt], phi[mt], plo[mt], shi[nt], slo[nt]);
        }
    }
    __syncthreads();   // F (sgT1) reads complete before overwrite
    float* Ff = (float*)F;
    #pragma unroll
    for (int nt = 0; nt < 2; ++nt) {
      const int ch = n0 + nt * 16 + li;
      const float bb = g1b[ch], bm = bn1m[ch];
      const float gs = bn1g[ch] * rsqrtf(bn1v[ch] + 1e-5f), gb = bn1b[ch];
      #pragma unroll
      for (int mt = 0; mt < 2; ++mt)
        #pragma unroll
        for (int r = 0; r < 4; ++r) {
          const int dn = m0 + mt * 16 + quad * 4 + r;
          const float rsv = s_ed[dn];
          Ff[dn * RSW + ch] = fmaxf((acc[mt][nt][r] * rsv + bb - bm) * gs + gb, 0.f);
        }
    }
  }
  __syncthreads();

  // ---- mean pool + MLP head
  const float* Ff = (const float*)F;
  float* s_red = s_alpha;
  {
    const int j = t & 127, q = t >> 7;
    float p = 0.f;
    for (int n = q * 16; n < q * 16 + 16; ++n) p += Ff[n * RSW + j];
    s_red[q * 128 + j] = p;
  }
  __syncthreads();
  if (t < FN) {
    float p = 0.f;
    #pragma unroll
    for (int q = 0; q < 8; ++q) p += s_red[q * 128 + t];
    s_es[t] = p * (1.f / 128.f);
  }
  __syncthreads();
  if (t < 512) {
    const int j = t & 63, part = t >> 6;
    float a = 0.f;
    #pragma unroll
    for (int k = part * 16; k < part * 16 + 16; ++k)
      a = fmaf(s_es[k], w1[k * 64 + j], a);
    s_ed[part * 64 + j] = a;
  }
  __syncthreads();
  if (t < 64) {
    float a = b1[t];
    #pragma unroll
    for (int p = 0; p < 8; ++p) a += s_ed[p * 64 + t];
    a = fmaxf(a, 0.f);
    float v = a * w2[t];
    #pragma unroll
    for (int off = 32; off > 0; off >>= 1) v += __shfl_down(v, off, 64);
    if (t == 0) out[b] = v + b2[0];
  }
}

extern "C" void kernel_launch(void* const* d_in, const int* in_sizes, int n_in,
                              void* d_out, int out_size, void* d_ws, size_t ws_size,
                              hipStream_t stream)
{
  const float* x    = (const float*)d_in[0];
  const int*   ei   = (const int*)d_in[1];
  const float* w_in = (const float*)d_in[2];
  const float* b_in = (const float*)d_in[3];
  const float* g0w  = (const float*)d_in[4];
  const float* g0as = (const float*)d_in[5];
  const float* g0ad = (const float*)d_in[6];
  const float* g0b  = (const float*)d_in[7];
  const float* bn0g = (const float*)d_in[8];
  const float* bn0b = (const float*)d_in[9];
  const float* bn0m = (const float*)d_in[10];
  const float* bn0v = (const float*)d_in[11];
  const float* g1w  = (const float*)d_in[12];
  const float* g1as = (const float*)d_in[13];
  const float* g1ad = (const float*)d_in[14];
  const float* g1b  = (const float*)d_in[15];
  const float* bn1g = (const float*)d_in[16];
  const float* bn1b = (const float*)d_in[17];
  const float* bn1m = (const float*)d_in[18];
  const float* bn1v = (const float*)d_in[19];
  const float* w1   = (const float*)d_in[20];
  const float* b1   = (const float*)d_in[21];
  const float* w2   = (const float*)d_in[22];
  const float* b2   = (const float*)d_in[23];

  gnn_fused_kernel<<<1024, 1024, 0, stream>>>(x, ei, w_in, b_in,
      g0w, g0as, g0ad, g0b, bn0g, bn0b, bn0m, bn0v,
      g1w, g1as, g1ad, g1b, bn1g, bn1b, bn1m, bn1v,
      w1, b1, w2, b2, (float*)d_out);
}

// Round 7
// 226.526 us; speedup vs baseline: 1.1700x; 1.1700x over previous
//
#include <hip/hip_runtime.h>

#define FN   128    // nodes per graph
#define HDIM 128    // hidden dim
#define NH   4      // heads, layer 0
#define HSZ  32     // head dim, layer 0
#define EB   1024   // base edges per graph
#define ET   1152   // edges incl. self loops
#define RSW  132    // padded LDS row stride (words)

typedef __attribute__((ext_vector_type(8))) short bf16x8;
typedef __attribute__((ext_vector_type(4))) float f32x4;
typedef unsigned int u32;

union U8 { bf16x8 v; u32 u[4]; };

__device__ __forceinline__ u32 pack_hl(float v) {
  const u32 u = __float_as_uint(v);
  const u32 hib = u & 0xFFFF0000u;
  const float lo = v - __uint_as_float(hib);
  return hib | (__float_as_uint(lo) >> 16);
}
__device__ __forceinline__ float unpack_val(u32 p) {
  return __uint_as_float(p & 0xFFFF0000u) + __uint_as_float(p << 16);
}

__device__ __forceinline__ void unpack_frag(const u32* __restrict__ q,
                                            bf16x8& hi, bf16x8& lo)
{
  const uint4 p0 = *(const uint4*)(q);
  const uint4 p1 = *(const uint4*)(q + 4);
  U8 H, L;
  H.u[0] = (p0.x >> 16) | (p0.y & 0xFFFF0000u);
  L.u[0] = (p0.x & 0xFFFFu) | (p0.y << 16);
  H.u[1] = (p0.z >> 16) | (p0.w & 0xFFFF0000u);
  L.u[1] = (p0.z & 0xFFFFu) | (p0.w << 16);
  H.u[2] = (p1.x >> 16) | (p1.y & 0xFFFF0000u);
  L.u[2] = (p1.x & 0xFFFFu) | (p1.y << 16);
  H.u[3] = (p1.z >> 16) | (p1.w & 0xFFFF0000u);
  L.u[3] = (p1.z & 0xFFFFu) | (p1.w << 16);
  hi = H.v; lo = L.v;
}

__device__ __forceinline__ void split8(const float* w, bf16x8& hi, bf16x8& lo)
{
  U8 H, L;
  #pragma unroll
  for (int p = 0; p < 4; ++p) {
    const u32 u0 = __float_as_uint(w[2 * p]);
    const u32 u1 = __float_as_uint(w[2 * p + 1]);
    const u32 h0 = u0 & 0xFFFF0000u, h1 = u1 & 0xFFFF0000u;
    const float l0 = w[2 * p]     - __uint_as_float(h0);
    const float l1 = w[2 * p + 1] - __uint_as_float(h1);
    H.u[p] = (u0 >> 16) | h1;
    L.u[p] = (__float_as_uint(l0) >> 16) | (__float_as_uint(l1) & 0xFFFF0000u);
  }
  hi = H.v; lo = L.v;
}

// MFMA GEMM core (r5-verified): acc[s][ct] = feat(packed shl) @ W tile.
// Wave tile 32 rows x 32 cols; kc-outer keeps B-frags at 32 VGPRs (no spill).
__device__ __forceinline__ void mfma_gemm_acc(const u32* __restrict__ shl,
                                              const float* __restrict__ W,
                                              int t, f32x4 acc[2][2])
{
  const int w = t >> 6, lane = t & 63;
  const int cg = w & 3, rh = w >> 2;
  const int m = lane & 15, quad = lane >> 4;
  const int n0 = cg * 32;

  #pragma unroll
  for (int s = 0; s < 2; ++s)
    #pragma unroll
    for (int ct = 0; ct < 2; ++ct) acc[s][ct] = (f32x4){0.f, 0.f, 0.f, 0.f};

  const u32* ap0 = shl + (rh * 32 + m) * RSW + quad * 8;
  const u32* ap1 = shl + (rh * 32 + 16 + m) * RSW + quad * 8;

  #pragma unroll
  for (int kc = 0; kc < 4; ++kc) {
    bf16x8 bhi[2], blo[2];
    #pragma unroll
    for (int ct = 0; ct < 2; ++ct) {
      const int n = n0 + ct * 16 + m;
      float wv[8];
      #pragma unroll
      for (int j = 0; j < 8; ++j) wv[j] = W[(kc * 32 + quad * 8 + j) * HDIM + n];
      split8(wv, bhi[ct], blo[ct]);
    }
    bf16x8 a0hi, a0lo, a1hi, a1lo;
    unpack_frag(ap0 + kc * 32, a0hi, a0lo);
    unpack_frag(ap1 + kc * 32, a1hi, a1lo);
    #pragma unroll
    for (int ct = 0; ct < 2; ++ct) {
      acc[0][ct] = __builtin_amdgcn_mfma_f32_16x16x32_bf16(a0hi, bhi[ct], acc[0][ct], 0, 0, 0);
      acc[0][ct] = __builtin_amdgcn_mfma_f32_16x16x32_bf16(a0lo, bhi[ct], acc[0][ct], 0, 0, 0);
      acc[0][ct] = __builtin_amdgcn_mfma_f32_16x16x32_bf16(a0hi, blo[ct], acc[0][ct], 0, 0, 0);
      acc[1][ct] = __builtin_amdgcn_mfma_f32_16x16x32_bf16(a1hi, bhi[ct], acc[1][ct], 0, 0, 0);
      acc[1][ct] = __builtin_amdgcn_mfma_f32_16x16x32_bf16(a1lo, bhi[ct], acc[1][ct], 0, 0, 0);
      acc[1][ct] = __builtin_amdgcn_mfma_f32_16x16x32_bf16(a1hi, blo[ct], acc[1][ct], 0, 0, 0);
    }
  }
}

// store acc -> sg (f32), C/D layout: col = lane&15, row = quad*4 + reg
__device__ __forceinline__ void store_acc(float* __restrict__ sg, int t,
                                          const f32x4 acc[2][2])
{
  const int w = t >> 6, lane = t & 63;
  const int cg = w & 3, rh = w >> 2;
  const int m = lane & 15, quad = lane >> 4;
  #pragma unroll
  for (int s = 0; s < 2; ++s) {
    const int row0 = rh * 32 + s * 16 + quad * 4;
    #pragma unroll
    for (int ct = 0; ct < 2; ++ct)
      #pragma unroll
      for (int r = 0; r < 4; ++r)
        sg[(row0 + r) * RSW + cg * 32 + ct * 16 + m] = acc[s][ct][r];
  }
}

// in-wave logits: partial (or full) es/ed over this wave's 32 cols, via
// 16-lane shfl_xor reduction; lane li==0 of each quad writes 8 rows.
__device__ __forceinline__ void wave_logits(const float* __restrict__ as_,
                                            const float* __restrict__ ad_,
                                            float* __restrict__ es,
                                            float* __restrict__ ed,
                                            int t, const f32x4 acc[2][2])
{
  const int w = t >> 6, lane = t & 63;
  const int cg = w & 3, rh = w >> 2;
  const int li = lane & 15, quad = lane >> 4;
  const float was0 = as_[cg * 32 + li],      wad0 = ad_[cg * 32 + li];
  const float was1 = as_[cg * 32 + 16 + li], wad1 = ad_[cg * 32 + 16 + li];
  float pes[8], ped[8];
  #pragma unroll
  for (int s = 0; s < 2; ++s)
    #pragma unroll
    for (int r = 0; r < 4; ++r) {
      pes[s * 4 + r] = acc[s][0][r] * was0 + acc[s][1][r] * was1;
      ped[s * 4 + r] = acc[s][0][r] * wad0 + acc[s][1][r] * wad1;
    }
  #pragma unroll
  for (int msk = 1; msk < 16; msk <<= 1)
    #pragma unroll
    for (int i = 0; i < 8; ++i) {
      pes[i] += __shfl_xor(pes[i], msk, 64);
      ped[i] += __shfl_xor(ped[i], msk, 64);
    }
  if (li == 0) {
    #pragma unroll
    for (int s = 0; s < 2; ++s)
      #pragma unroll
      for (int r = 0; r < 4; ++r) {
        const int row = rh * 32 + s * 16 + quad * 4 + r;
        es[cg * 128 + row] = pes[s * 4 + r];
        ed[cg * 128 + row] = ped[s * 4 + r];
      }
  }
}

// ---------------- fully fused per-graph GNN (1024 threads, 16 waves) ----------------
__global__ __launch_bounds__(1024) void gnn_fused_kernel(
    const float* __restrict__ x, const int* __restrict__ ei,
    const float* __restrict__ w_in, const float* __restrict__ b_in,
    const float* __restrict__ g0w, const float* __restrict__ g0as,
    const float* __restrict__ g0ad, const float* __restrict__ g0b,
    const float* __restrict__ bn0g, const float* __restrict__ bn0b,
    const float* __restrict__ bn0m, const float* __restrict__ bn0v,
    const float* __restrict__ g1w, const float* __restrict__ g1as,
    const float* __restrict__ g1ad, const float* __restrict__ g1b,
    const float* __restrict__ bn1g, const float* __restrict__ bn1b,
    const float* __restrict__ bn1m, const float* __restrict__ bn1v,
    const float* __restrict__ w1, const float* __restrict__ b1,
    const float* __restrict__ w2, const float* __restrict__ b2,
    float* __restrict__ out)
{
  __shared__ u32   shl[FN * RSW];       // packed hi|lo features
  __shared__ float sg[FN * RSW];        // GEMM output (f32)
  __shared__ float s_alpha[NH * ET];    // exp values
  __shared__ int   s_src[ET];           // src | dst<<8
  __shared__ int   s_rp[FN + 1];
  __shared__ float s_es[512];           // [head][n] (l0) / partials (l1)
  __shared__ float s_ed[512];

  const int t = threadIdx.x;
  const int b = blockIdx.x;
  f32x4 acc[2][2];

  // ================= per-block CSR build =================
  int* s_deg  = (int*)s_alpha;
  int* s_fill = s_deg + 128;
  const int e_dst = ei[EB + t];
  const int e_src = ei[t];
  if (t < 2 * FN) s_deg[t] = 0;
  __syncthreads();
  atomicAdd(&s_deg[e_dst], 1);

  // ---- input projection + ReLU -> shl
  {
    const int j = t & 127, q = t >> 7;
    const float wv = w_in[j], bv = b_in[j];
    for (int n = q * 16; n < q * 16 + 16; ++n) {
      const float v = fmaxf(fmaf(x[(size_t)b * FN + n], wv, bv), 0.f);
      shl[n * RSW + j] = pack_hl(v);
    }
  }
  __syncthreads();
  if (t < 64) {                         // wave-0 exclusive scan of (deg+1)
    const int v0 = s_deg[2 * t] + 1, v1 = s_deg[2 * t + 1] + 1;
    const int p = v0 + v1;
    int sc = p;
    #pragma unroll
    for (int off = 1; off < 64; off <<= 1) {
      const int o = __shfl_up(sc, off, 64);
      if (t >= off) sc += o;
    }
    s_rp[2 * t] = sc - p;
    s_rp[2 * t + 1] = sc - v1;
    if (t == 63) s_rp[128] = sc;        // == ET
  }
  __syncthreads();
  {
    const int p = s_rp[e_dst] + atomicAdd(&s_fill[e_dst], 1);
    s_src[p] = e_src | (e_dst << 8);
  }
  if (t < FN) s_src[s_rp[t + 1] - 1] = t | (t << 8);
  __syncthreads();

  // ======================= GAT layer 0 =======================
  mfma_gemm_acc(shl, g0w, t, acc);
  store_acc(sg, t, acc);
  wave_logits(g0as, g0ad, s_es, s_ed, t, acc);   // head = wave's col-group
  __syncthreads();

  // single-pass edge-parallel softmax numerators (logits bounded, no max)
  {
    #pragma unroll
    for (int i = t; i < NH * EB; i += 1024) {       // h = i>>10, e = i&1023
      const int h = i >> 10, e = i & 1023;
      const int sd = s_src[e];
      float v = s_es[h * 128 + (sd & 127)] + s_ed[h * 128 + (sd >> 8)];
      v = (v > 0.f) ? v : 0.2f * v;
      s_alpha[h * ET + e] = __expf(v);
    }
    if (t < 512) {                                  // tail edges 1024..1151
      const int h = t >> 7, e = EB + (t & 127);
      const int sd = s_src[e];
      float v = s_es[h * 128 + (sd & 127)] + s_ed[h * 128 + (sd >> 8)];
      v = (v > 0.f) ? v : 0.2f * v;
      s_alpha[h * ET + e] = __expf(v);
    }
  }
  __syncthreads();

  // aggregation + 1/sum + bias + BN + ReLU -> shl  (thread: 2 nodes x 8 cols)
  {
    const int cg = t & 15, rg = t >> 4;
    const int c0 = cg * 4, c1 = 64 + cg * 4;
    const int hhA = cg >> 3, hhB = 2 + (cg >> 3);
    const float4 bbA = *(const float4*)&g0b[c0],  bbB = *(const float4*)&g0b[c1];
    const float4 bmA = *(const float4*)&bn0m[c0], bmB = *(const float4*)&bn0m[c1];
    const float4 bvA = *(const float4*)&bn0v[c0], bvB = *(const float4*)&bn0v[c1];
    const float4 bgA = *(const float4*)&bn0g[c0], bgB = *(const float4*)&bn0g[c1];
    const float4 btA = *(const float4*)&bn0b[c0], btB = *(const float4*)&bn0b[c1];
    const float g0_ = bgA.x * rsqrtf(bvA.x + 1e-5f), g1_ = bgA.y * rsqrtf(bvA.y + 1e-5f);
    const float g2_ = bgA.z * rsqrtf(bvA.z + 1e-5f), g3_ = bgA.w * rsqrtf(bvA.w + 1e-5f);
    const float g4_ = bgB.x * rsqrtf(bvB.x + 1e-5f), g5_ = bgB.y * rsqrtf(bvB.y + 1e-5f);
    const float g6_ = bgB.z * rsqrtf(bvB.z + 1e-5f), g7_ = bgB.w * rsqrtf(bvB.w + 1e-5f);
    #pragma unroll
    for (int h2 = 0; h2 < 2; ++h2) {
      const int n = rg + h2 * 64;
      const int e0 = s_rp[n], e1 = s_rp[n + 1];
      float sumA = 0.f, sumB = 0.f;
      for (int e = e0; e < e1; ++e) {
        sumA += s_alpha[hhA * ET + e];
        sumB += s_alpha[hhB * ET + e];
      }
      const float rsvA = 1.f / sumA, rsvB = 1.f / sumB;
      float4 a0 = make_float4(0.f, 0.f, 0.f, 0.f);
      float4 a1 = make_float4(0.f, 0.f, 0.f, 0.f);
      for (int e = e0; e < e1; ++e) {
        const int s = s_src[e] & 127;
        const float alA = s_alpha[hhA * ET + e];
        const float alB = s_alpha[hhB * ET + e];
        const float4 v0 = *(const float4*)(sg + s * RSW + c0);
        const float4 v1 = *(const float4*)(sg + s * RSW + c1);
        a0.x = fmaf(alA, v0.x, a0.x); a0.y = fmaf(alA, v0.y, a0.y);
        a0.z = fmaf(alA, v0.z, a0.z); a0.w = fmaf(alA, v0.w, a0.w);
        a1.x = fmaf(alB, v1.x, a1.x); a1.y = fmaf(alB, v1.y, a1.y);
        a1.z = fmaf(alB, v1.z, a1.z); a1.w = fmaf(alB, v1.w, a1.w);
      }
      uint4 p0, p1;
      p0.x = pack_hl(fmaxf((a0.x * rsvA + bbA.x - bmA.x) * g0_ + btA.x, 0.f));
      p0.y = pack_hl(fmaxf((a0.y * rsvA + bbA.y - bmA.y) * g1_ + btA.y, 0.f));
      p0.z = pack_hl(fmaxf((a0.z * rsvA + bbA.z - bmA.z) * g2_ + btA.z, 0.f));
      p0.w = pack_hl(fmaxf((a0.w * rsvA + bbA.w - bmA.w) * g3_ + btA.w, 0.f));
      p1.x = pack_hl(fmaxf((a1.x * rsvB + bbB.x - bmB.x) * g4_ + btB.x, 0.f));
      p1.y = pack_hl(fmaxf((a1.y * rsvB + bbB.y - bmB.y) * g5_ + btB.y, 0.f));
      p1.z = pack_hl(fmaxf((a1.z * rsvB + bbB.z - bmB.z) * g6_ + btB.z, 0.f));
      p1.w = pack_hl(fmaxf((a1.w * rsvB + bbB.w - bmB.w) * g7_ + btB.w, 0.f));
      *(uint4*)(shl + n * RSW + c0) = p0;
      *(uint4*)(shl + n * RSW + c1) = p1;
    }
  }
  __syncthreads();

  // ======================= GAT layer 1 (1 head) =======================
  mfma_gemm_acc(shl, g1w, t, acc);
  store_acc(sg, t, acc);
  wave_logits(g1as, g1ad, s_es, s_ed, t, acc);   // partials per col-group
  __syncthreads();

  // combine 4 col-group partials
  if (t < 128) {
    s_es[t] = s_es[t] + s_es[t + 128] + s_es[t + 256] + s_es[t + 384];
  } else if (t < 256) {
    const int n = t - 128;
    s_ed[n] = s_ed[n] + s_ed[n + 128] + s_ed[n + 256] + s_ed[n + 384];
  }
  __syncthreads();

  // edge-parallel numerators (1 head)
  for (int i = t; i < ET; i += 1024) {
    const int sd = s_src[i];
    float v = s_es[sd & 127] + s_ed[sd >> 8];
    v = (v > 0.f) ? v : 0.2f * v;
    s_alpha[i] = __expf(v);
  }
  __syncthreads();

  // aggregation + epilogue -> shl
  {
    const int cg = t & 15, rg = t >> 4;
    const int c0 = cg * 4, c1 = 64 + cg * 4;
    const float4 bbA = *(const float4*)&g1b[c0],  bbB = *(const float4*)&g1b[c1];
    const float4 bmA = *(const float4*)&bn1m[c0], bmB = *(const float4*)&bn1m[c1];
    const float4 bvA = *(const float4*)&bn1v[c0], bvB = *(const float4*)&bn1v[c1];
    const float4 bgA = *(const float4*)&bn1g[c0], bgB = *(const float4*)&bn1g[c1];
    const float4 btA = *(const float4*)&bn1b[c0], btB = *(const float4*)&bn1b[c1];
    const float g0_ = bgA.x * rsqrtf(bvA.x + 1e-5f), g1_ = bgA.y * rsqrtf(bvA.y + 1e-5f);
    const float g2_ = bgA.z * rsqrtf(bvA.z + 1e-5f), g3_ = bgA.w * rsqrtf(bvA.w + 1e-5f);
    const float g4_ = bgB.x * rsqrtf(bvB.x + 1e-5f), g5_ = bgB.y * rsqrtf(bvB.y + 1e-5f);
    const float g6_ = bgB.z * rsqrtf(bvB.z + 1e-5f), g7_ = bgB.w * rsqrtf(bvB.w + 1e-5f);
    #pragma unroll
    for (int h2 = 0; h2 < 2; ++h2) {
      const int n = rg + h2 * 64;
      const int e0 = s_rp[n], e1 = s_rp[n + 1];
      float sum = 0.f;
      for (int e = e0; e < e1; ++e) sum += s_alpha[e];
      const float rsv = 1.f / sum;
      float4 a0 = make_float4(0.f, 0.f, 0.f, 0.f);
      float4 a1 = make_float4(0.f, 0.f, 0.f, 0.f);
      for (int e = e0; e < e1; ++e) {
        const int s = s_src[e] & 127;
        const float al = s_alpha[e];
        const float4 v0 = *(const float4*)(sg + s * RSW + c0);
        const float4 v1 = *(const float4*)(sg + s * RSW + c1);
        a0.x = fmaf(al, v0.x, a0.x); a0.y = fmaf(al, v0.y, a0.y);
        a0.z = fmaf(al, v0.z, a0.z); a0.w = fmaf(al, v0.w, a0.w);
        a1.x = fmaf(al, v1.x, a1.x); a1.y = fmaf(al, v1.y, a1.y);
        a1.z = fmaf(al, v1.z, a1.z); a1.w = fmaf(al, v1.w, a1.w);
      }
      uint4 p0, p1;
      p0.x = pack_hl(fmaxf((a0.x * rsv + bbA.x - bmA.x) * g0_ + btA.x, 0.f));
      p0.y = pack_hl(fmaxf((a0.y * rsv + bbA.y - bmA.y) * g1_ + btA.y, 0.f));
      p0.z = pack_hl(fmaxf((a0.z * rsv + bbA.z - bmA.z) * g2_ + btA.z, 0.f));
      p0.w = pack_hl(fmaxf((a0.w * rsv + bbA.w - bmA.w) * g3_ + btA.w, 0.f));
      p1.x = pack_hl(fmaxf((a1.x * rsv + bbB.x - bmB.x) * g4_ + btB.x, 0.f));
      p1.y = pack_hl(fmaxf((a1.y * rsv + bbB.y - bmB.y) * g5_ + btB.y, 0.f));
      p1.z = pack_hl(fmaxf((a1.z * rsv + bbB.z - bmB.z) * g6_ + btB.z, 0.f));
      p1.w = pack_hl(fmaxf((a1.w * rsv + bbB.w - bmB.w) * g7_ + btB.w, 0.f));
      *(uint4*)(shl + n * RSW + c0) = p0;
      *(uint4*)(shl + n * RSW + c1) = p1;
    }
  }
  __syncthreads();

  // ---- mean pool (packed shl) + MLP head
  float* s_red = s_alpha;
  {
    const int j = t & 127, q = t >> 7;
    float p = 0.f;
    for (int n = q * 16; n < q * 16 + 16; ++n) p += unpack_val(shl[n * RSW + j]);
    s_red[q * 128 + j] = p;
  }
  __syncthreads();
  if (t < FN) {
    float p = 0.f;
    #pragma unroll
    for (int q = 0; q < 8; ++q) p += s_red[q * 128 + t];
    s_es[t] = p * (1.f / 128.f);
  }
  __syncthreads();
  if (t < 512) {
    const int j = t & 63, part = t >> 6;
    float a = 0.f;
    #pragma unroll
    for (int k = part * 16; k < part * 16 + 16; ++k)
      a = fmaf(s_es[k], w1[k * 64 + j], a);
    s_ed[part * 64 + j] = a;
  }
  __syncthreads();
  if (t < 64) {
    float a = b1[t];
    #pragma unroll
    for (int p = 0; p < 8; ++p) a += s_ed[p * 64 + t];
    a = fmaxf(a, 0.f);
    float v = a * w2[t];
    #pragma unroll
    for (int off = 32; off > 0; off >>= 1) v += __shfl_down(v, off, 64);
    if (t == 0) out[b] = v + b2[0];
  }
}

extern "C" void kernel_launch(void* const* d_in, const int* in_sizes, int n_in,
                              void* d_out, int out_size, void* d_ws, size_t ws_size,
                              hipStream_t stream)
{
  const float* x    = (const float*)d_in[0];
  const int*   ei   = (const int*)d_in[1];
  const float* w_in = (const float*)d_in[2];
  const float* b_in = (const float*)d_in[3];
  const float* g0w  = (const float*)d_in[4];
  const float* g0as = (const float*)d_in[5];
  const float* g0ad = (const float*)d_in[6];
  const float* g0b  = (const float*)d_in[7];
  const float* bn0g = (const float*)d_in[8];
  const float* bn0b = (const float*)d_in[9];
  const float* bn0m = (const float*)d_in[10];
  const float* bn0v = (const float*)d_in[11];
  const float* g1w  = (const float*)d_in[12];
  const float* g1as = (const float*)d_in[13];
  const float* g1ad = (const float*)d_in[14];
  const float* g1b  = (const float*)d_in[15];
  const float* bn1g = (const float*)d_in[16];
  const float* bn1b = (const float*)d_in[17];
  const float* bn1m = (const float*)d_in[18];
  const float* bn1v = (const float*)d_in[19];
  const float* w1   = (const float*)d_in[20];
  const float* b1   = (const float*)d_in[21];
  const float* w2   = (const float*)d_in[22];
  const float* b2   = (const float*)d_in[23];

  gnn_fused_kernel<<<1024, 1024, 0, stream>>>(x, ei, w_in, b_in,
      g0w, g0as, g0ad, g0b, bn0g, bn0b, bn0m, bn0v,
      g1w, g1as, g1ad, g1b, bn1g, bn1b, bn1m, bn1v,
      w1, b1, w2, b2, (float*)d_out);
}